// Round 6
// baseline (779.940 us; speedup 1.0000x reference)
//
#include <hip/hip_runtime.h>
#include <hip/hip_bf16.h>

typedef __hip_bfloat16 bf16;
typedef unsigned short u16;
typedef unsigned int u32;
typedef __attribute__((ext_vector_type(8))) short short8;
typedef __attribute__((ext_vector_type(4))) float floatx4;

#define N_NODES 50000
#define N_EDGES 800000
#define DIM 128
#define NB2 1563           // ceil(50000/32); bucket = dst >> 5
#define NB2A 1792          // padded
#define CAP2 768           // per-bucket capacity (mean 512, sd ~23 -> 11 sigma)
#define T_EDGES 4096       // edges per sort1 tile -> 196 tiles
#define NT1 196            // sort1 blocks in K1
#define XCHUNKS 3125       // x-convert chunks (2048 floats each)
#define WROW 136           // padded row stride (u16): 272B rows, 16B-aligned
#define WIMG (128 * WROW)  // 17408 u16 per W image
#define HROW 132           // f32 h-tile row stride (528B): breaks 16-way bank conflict on frag reads
// stats: sum at stats[l*2048 + c*16], sq at [.. + 8] -> one 64B line per accumulator

__device__ __forceinline__ u16 f2bfbits(float f) {
    bf16 h = __float2bfloat16(f);
    return *(u16*)&h;
}
__device__ __forceinline__ unsigned pack2(float a, float b) {
    return (unsigned)f2bfbits(a) | ((unsigned)f2bfbits(b) << 16);
}
__device__ __forceinline__ float lo2f(u32 u) { u32 v = u << 16; return __builtin_bit_cast(float, v); }
__device__ __forceinline__ float hi2f(u32 u) { u32 v = u & 0xFFFF0000u; return __builtin_bit_cast(float, v); }
__device__ __forceinline__ float b162f(u16 u) { u32 v = (u32)u << 16; return __builtin_bit_cast(float, v); }

// ---------------- K1: sort1 tiles (bid<196) || x->bf16 || W->bf16 images ----------------
__launch_bounds__(256)
__global__ void k1_kernel(const float* __restrict__ x, const int* __restrict__ ei,
                          u32* __restrict__ xb,
                          const float* __restrict__ W1, const float* __restrict__ W2,
                          u16* __restrict__ w1i, u16* __restrict__ w2i,
                          u32* __restrict__ gbuck, int* __restrict__ gcur) {
    __shared__ int hist[NB2A];
    __shared__ int cur[NB2A];
    __shared__ int gbase[NB2A];
    __shared__ int sdet;
    int t = threadIdx.x, bid = blockIdx.x;

    if (bid < NT1) {
        if (t == 0) sdet = 0;
        for (int i = t; i < NB2A; i += 256) { hist[i] = 0; cur[i] = 0; }
        __syncthreads();
        if (t < 64) { if (ei[2 * t + 1] != 0) atomicOr(&sdet, 1); }
        __syncthreads();
        int is64 = (sdet == 0);
        int e0 = bid * T_EDGES;
        int n = N_EDGES - e0; if (n > T_EDGES) n = T_EDGES;
        u32 ed[T_EDGES / 256];
        #pragma unroll
        for (int j = 0; j < T_EDGES / 256; j++) {
            int idx = j * 256 + t;
            if (idx < n) {
                int e = e0 + idx;
                int js = e, jd = N_EDGES + e;
                if (is64) { js = 2 * e; jd = 2 * (N_EDGES + e); }
                u32 p = (u32)ei[js] | ((u32)ei[jd] << 16);
                ed[j] = p;
                atomicAdd(&hist[p >> 21], 1);      // bucket = dst>>5 = p>>21
            }
        }
        __syncthreads();
        // reserve dense global runs; gcur stride-16: one 64B line per bucket counter
        for (int i = t; i < NB2; i += 256) {
            int c = hist[i];
            gbase[i] = c ? atomicAdd(&gcur[i * 16], c) : 0;
        }
        __syncthreads();
        #pragma unroll
        for (int j = 0; j < T_EDGES / 256; j++) {
            int idx = j * 256 + t;
            if (idx < n) {
                u32 p = ed[j];
                int b = p >> 21;
                int pos = gbase[b] + atomicAdd(&cur[b], 1);
                gbuck[(long)b * CAP2 + pos] = p;
            }
        }
    } else if (bid < NT1 + XCHUNKS) {
        int uu = bid - NT1;
        int i = (uu * 256 + t) * 8;
        floatx4 v0 = *(const floatx4*)&x[i];
        floatx4 v1 = *(const floatx4*)&x[i + 4];
        uint4 r;
        r.x = pack2(v0[0], v0[1]); r.y = pack2(v0[2], v0[3]);
        r.z = pack2(v1[0], v1[1]); r.w = pack2(v1[2], v1[3]);
        *(uint4*)&xb[i / 2] = r;
    } else {
        int which = bid - NT1 - XCHUNKS;           // 0 or 1
        const float* W = which ? W2 : W1;
        u16* wi = which ? w2i : w1i;
        #pragma unroll 4
        for (int j = 0; j < 68; j++) {             // 68*256 = 17408 exactly
            int q = j * 256 + t;
            int r = q / WROW, c = q - r * WROW;
            wi[q] = (c < 128) ? f2bfbits(W[r * 128 + c]) : (u16)0;
        }
    }
}

// ---------------- K2: fused aggregate (LDS f32 atomics) + GEMM1 (one bucket/block) ----------------
// h-tile accumulated in LDS via ds_add_f32: no per-node serial chains, no counting sort.
// Edge batches are fully independent -> deep load pipelining. B-fragments from global W1
// image (L2 broadcast), A-fragments packed f32->bf16 from the LDS tile.
__launch_bounds__(256)
__global__ void aggGemm1_kernel(const u32* __restrict__ xb, const u32* __restrict__ gbuck,
                                const int* __restrict__ gcur, const float* __restrict__ epsp,
                                const u16* __restrict__ w1i, const float* __restrict__ bias,
                                u16* __restrict__ y1, float* __restrict__ ostat) {
    __shared__ u32 sbuf[CAP2];        // 3 KB edge words
    __shared__ float hs[32 * HROW];   // 16.9 KB f32 h-tile, padded stride
    __shared__ float sSum[128], sSq[128];
    int t = threadIdx.x, lane = t & 63, wv = t >> 6;
    int b = blockIdx.x;
    int n = gcur[b * 16]; if (n > CAP2) n = CAP2;
    long base = (long)b * CAP2;

    if (t < 128) { sSum[t] = 0.f; sSq[t] = 0.f; }
    // stage edge words (coalesced)
    for (int i = t; i < n; i += 256) sbuf[i] = gbuck[base + i];
    // init h rows with (1+eps)*self (rows past N zeroed for the MFMA)
    float ep1 = 1.0f + epsp[0];
    for (int nn = wv; nn < 32; nn += 4) {
        int node = b * 32 + nn;
        float ax = 0.f, ay = 0.f;
        if (node < N_NODES) {
            u32 self = xb[node * 64 + lane];
            ax = ep1 * lo2f(self); ay = ep1 * hi2f(self);
        }
        hs[nn * HROW + 2 * lane] = ax;
        hs[nn * HROW + 2 * lane + 1] = ay;
    }
    __syncthreads();

    // stream edges: wave wv takes e = wv, wv+4, ... ; batches of 8 are independent
    int nw = (n > wv) ? ((n - wv + 3) >> 2) : 0;   // count of k with wv+4k < n
    int i = 0;
    for (; i + 8 <= nw; i += 8) {
        u32 p[8], uv[8];
        #pragma unroll
        for (int j = 0; j < 8; j++) p[j] = sbuf[wv + 4 * (i + j)];   // LDS broadcast
        #pragma unroll
        for (int j = 0; j < 8; j++) uv[j] = xb[(p[j] & 0xFFFF) * 64 + lane];
        #pragma unroll
        for (int j = 0; j < 8; j++) {
            int d = (p[j] >> 16) & 31;
            float* hp = &hs[d * HROW + 2 * lane];
            atomicAdd(hp, lo2f(uv[j]));            // ds_add_f32
            atomicAdd(hp + 1, hi2f(uv[j]));
        }
    }
    for (; i < nw; i++) {
        u32 p0 = sbuf[wv + 4 * i];
        u32 u0 = xb[(p0 & 0xFFFF) * 64 + lane];
        int d = (p0 >> 16) & 31;
        float* hp = &hs[d * HROW + 2 * lane];
        atomicAdd(hp, lo2f(u0));
        atomicAdd(hp + 1, hi2f(u0));
    }
    __syncthreads();

    // GEMM1: wave wv -> row-tile rt = wv&1 (16 rows), col-group ng = wv>>1 (4 x 16 cols)
    int col0 = lane & 15, quad = lane >> 4;
    int rt = wv & 1, ng = wv >> 1;
    short8 afr[4];
    #pragma unroll
    for (int ks = 0; ks < 4; ks++) {
        const float* hp = &hs[(rt * 16 + col0) * HROW + ks * 32 + quad * 8];
        floatx4 f0 = *(const floatx4*)hp;
        floatx4 f1 = *(const floatx4*)(hp + 4);
        u32 rr[4] = {pack2(f0[0], f0[1]), pack2(f0[2], f0[3]),
                     pack2(f1[0], f1[1]), pack2(f1[2], f1[3])};
        afr[ks] = *(short8*)rr;
    }
    floatx4 acc[4];
    #pragma unroll
    for (int j = 0; j < 4; j++) acc[j] = (floatx4){0.f, 0.f, 0.f, 0.f};
    #pragma unroll
    for (int ks = 0; ks < 4; ks++) {
        #pragma unroll
        for (int j = 0; j < 4; j++) {
            int nt = ng * 4 + j;
            short8 bfr = *(const short8*)&w1i[(nt * 16 + col0) * WROW + ks * 32 + quad * 8];
            acc[j] = __builtin_amdgcn_mfma_f32_16x16x32_bf16(afr[ks], bfr, acc[j], 0, 0, 0);
        }
    }
    int rtile = b * 32 + rt * 16;
    if (rtile < N_NODES) {                          // tiles 16-aligned; N%16==0
        #pragma unroll
        for (int j = 0; j < 4; j++) {
            int col = (ng * 4 + j) * 16 + col0;
            float bb = bias[col];
            float o0 = acc[j][0] + bb, o1 = acc[j][1] + bb;
            float o2 = acc[j][2] + bb, o3 = acc[j][3] + bb;
            int rbase = rtile + quad * 4;
            y1[(rbase + 0) * DIM + col] = f2bfbits(o0);
            y1[(rbase + 1) * DIM + col] = f2bfbits(o1);
            y1[(rbase + 2) * DIM + col] = f2bfbits(o2);
            y1[(rbase + 3) * DIM + col] = f2bfbits(o3);
            float s = o0 + o1 + o2 + o3;
            float q = o0 * o0 + o1 * o1 + o2 * o2 + o3 * o3;
            s += __shfl_xor(s, 16); s += __shfl_xor(s, 32);
            q += __shfl_xor(q, 16); q += __shfl_xor(q, 32);
            if (quad == 0) { atomicAdd(&sSum[col], s); atomicAdd(&sSq[col], q); }
        }
    }
    __syncthreads();
    if (t < 128) {
        atomicAdd(&ostat[t * 16], sSum[t]);
        atomicAdd(&ostat[t * 16 + 8], sSq[t]);
    }
}

// ---------------- K3: GEMM2 with fused BN1+ReLU on A (128 rows/block, 2 tiles/wave) ----------------
__launch_bounds__(256)
__global__ void gemm2_kernel(const u16* __restrict__ Ap, const u16* __restrict__ wimg,
                             const float* __restrict__ bias,
                             const float* __restrict__ gamma, const float* __restrict__ beta,
                             const float* __restrict__ gstat,
                             u16* __restrict__ Yp, float* __restrict__ ostat) {
    __shared__ u16 sW[WIMG];                                   // 34816 B padded image
    __shared__ float sScale[128], sShift[128], sBias[128], sSum[128], sSq[128];
    int t = threadIdx.x, lane = t & 63, wv = t >> 6;

    #pragma unroll
    for (int it = 0; it < 9; it++) {
        int q = it * 256 + t;
        if (q < WIMG / 8) *(uint4*)&sW[q * 8] = ((const uint4*)wimg)[q];
    }
    if (t < 128) {
        sSum[t] = 0.f; sSq[t] = 0.f; sBias[t] = bias[t];
        float m = gstat[t * 16] * (1.0f / N_NODES);
        float v = fmaxf(gstat[t * 16 + 8] * (1.0f / N_NODES) - m * m, 0.0f);
        float rs = rsqrtf(v + 1e-5f);
        float sc = gamma[t] * rs;
        sScale[t] = sc;
        sShift[t] = beta[t] - m * sc;
    }
    __syncthreads();

    int col0 = lane & 15, quad = lane >> 4;
    int row0 = blockIdx.x * 128 + wv * 32;

    short8 afr[2][4];
    #pragma unroll
    for (int tt = 0; tt < 2; tt++) {
        int mrow = row0 + tt * 16 + col0;
        if (mrow > N_NODES - 1) mrow = N_NODES - 1;            // clamp inside y1
        #pragma unroll
        for (int ks = 0; ks < 4; ks++)
            afr[tt][ks] = *(const short8*)&Ap[mrow * DIM + ks * 32 + quad * 8];
    }
    #pragma unroll
    for (int tt = 0; tt < 2; tt++)
        #pragma unroll
        for (int ks = 0; ks < 4; ks++) {
            int kb = ks * 32 + quad * 8;
            short8 a = afr[tt][ks], r;
            #pragma unroll
            for (int j = 0; j < 8; j++) {
                float f = b162f((u16)a[j]);
                r[j] = (short)f2bfbits(fmaxf(fmaf(f, sScale[kb + j], sShift[kb + j]), 0.f));
            }
            afr[tt][ks] = r;
        }

    floatx4 acc[2][8];
    #pragma unroll
    for (int tt = 0; tt < 2; tt++)
        #pragma unroll
        for (int nt = 0; nt < 8; nt++) acc[tt][nt] = (floatx4){0.f, 0.f, 0.f, 0.f};
    #pragma unroll
    for (int ks = 0; ks < 4; ks++)
        #pragma unroll
        for (int nt = 0; nt < 8; nt++) {
            short8 bfr = *(const short8*)&sW[(nt * 16 + col0) * WROW + ks * 32 + quad * 8];
            acc[0][nt] = __builtin_amdgcn_mfma_f32_16x16x32_bf16(afr[0][ks], bfr, acc[0][nt], 0, 0, 0);
            acc[1][nt] = __builtin_amdgcn_mfma_f32_16x16x32_bf16(afr[1][ks], bfr, acc[1][nt], 0, 0, 0);
        }

    #pragma unroll
    for (int tt = 0; tt < 2; tt++) {
        int rtile = row0 + tt * 16;
        if (rtile >= N_NODES) break;
        #pragma unroll
        for (int nt = 0; nt < 8; nt++) {
            int col = nt * 16 + col0;
            float bb = sBias[col];
            float o0 = acc[tt][nt][0] + bb, o1 = acc[tt][nt][1] + bb;
            float o2 = acc[tt][nt][2] + bb, o3 = acc[tt][nt][3] + bb;
            int rbase = rtile + quad * 4;
            Yp[(rbase + 0) * DIM + col] = f2bfbits(o0);
            Yp[(rbase + 1) * DIM + col] = f2bfbits(o1);
            Yp[(rbase + 2) * DIM + col] = f2bfbits(o2);
            Yp[(rbase + 3) * DIM + col] = f2bfbits(o3);
            float s = o0 + o1 + o2 + o3;
            float q = o0 * o0 + o1 * o1 + o2 * o2 + o3 * o3;
            s += __shfl_xor(s, 16); s += __shfl_xor(s, 32);
            q += __shfl_xor(q, 16); q += __shfl_xor(q, 32);
            if (quad == 0) { atomicAdd(&sSum[col], s); atomicAdd(&sSq[col], q); }
        }
    }
    __syncthreads();
    if (t < 128) {
        atomicAdd(&ostat[t * 16], sSum[t]);
        atomicAdd(&ostat[t * 16 + 8], sSq[t]);
    }
}

// ---------------- K4: final BN2 + ReLU: y2 bf16 -> out fp32 ----------------
__global__ void output_kernel(const u32* __restrict__ Y,
                              const float* __restrict__ gstat,
                              const float* __restrict__ gamma, const float* __restrict__ beta,
                              float* __restrict__ out) {
    __shared__ float sScale[128], sShift[128];
    int t = threadIdx.x;
    if (t < 128) {
        float m = gstat[t * 16] * (1.0f / N_NODES);
        float v = fmaxf(gstat[t * 16 + 8] * (1.0f / N_NODES) - m * m, 0.0f);
        float rs = rsqrtf(v + 1e-5f);
        float sc = gamma[t] * rs;
        sScale[t] = sc;
        sShift[t] = beta[t] - m * sc;
    }
    __syncthreads();
    int i = (blockIdx.x * 256 + t) * 8;
    int c = i & 127;
    uint4 v = *(const uint4*)&Y[i / 2];
    u32 w[4] = {v.x, v.y, v.z, v.w};
    floatx4 o0, o1;
    #pragma unroll
    for (int j = 0; j < 4; j++) {
        float lo = lo2f(w[j]), hi = hi2f(w[j]);
        float r0 = fmaxf(fmaf(lo, sScale[c + 2 * j],     sShift[c + 2 * j]),     0.f);
        float r1 = fmaxf(fmaf(hi, sScale[c + 2 * j + 1], sShift[c + 2 * j + 1]), 0.f);
        if (j < 2) { o0[2 * j] = r0; o0[2 * j + 1] = r1; }
        else       { o1[2 * (j - 2)] = r0; o1[2 * (j - 2) + 1] = r1; }
    }
    *(floatx4*)&out[i] = o0;
    *(floatx4*)&out[i + 4] = o1;
}

extern "C" void kernel_launch(void* const* d_in, const int* in_sizes, int n_in,
                              void* d_out, int out_size, void* d_ws, size_t ws_size,
                              hipStream_t stream) {
    const float* x   = (const float*)d_in[0];
    const int* eraw  = (const int*)d_in[1];
    const float* eps = (const float*)d_in[3];
    const float* W1  = (const float*)d_in[4];
    const float* b1  = (const float*)d_in[5];
    const float* g1  = (const float*)d_in[6];
    const float* be1 = (const float*)d_in[7];
    const float* W2  = (const float*)d_in[8];
    const float* b2  = (const float*)d_in[9];
    const float* g2  = (const float*)d_in[10];
    const float* be2 = (const float*)d_in[11];

    char* ws = (char*)d_ws;
    size_t off = 0;
    u32* xb = (u32*)(ws + off);          off += (size_t)N_NODES * DIM * 2;   // bf16 x
    u16* y1 = (u16*)(ws + off);          off += (size_t)N_NODES * DIM * 2;   // bf16 y1
    u16* y2 = (u16*)(ws + off);          off += (size_t)N_NODES * DIM * 2;   // bf16 y2
    float* stats = (float*)(ws + off);   off += 4096 * 4;                    // strided stats
    float* st1 = stats;                  // layer-1: sum @ [c*16], sq @ [c*16+8]
    float* st2 = stats + 2048;           // layer-2
    u16* w1i = (u16*)(ws + off);         off += (size_t)WIMG * 2;            // bf16 W1 image
    u16* w2i = (u16*)(ws + off);         off += (size_t)WIMG * 2;            // bf16 W2 image
    u32* gbuck = (u32*)(ws + off);       off += (size_t)NB2 * CAP2 * 4;      // 4.8 MB
    int* gcur = (int*)(ws + off);        off += (size_t)((NB2 * 16 + 255) & ~255) * 4;

    hipMemsetAsync(gcur, 0, (size_t)NB2 * 16 * 4, stream);
    hipMemsetAsync(stats, 0, 4096 * 4, stream);

    k1_kernel<<<NT1 + XCHUNKS + 2, 256, 0, stream>>>(x, eraw, xb, W1, W2, w1i, w2i, gbuck, gcur);
    aggGemm1_kernel<<<NB2, 256, 0, stream>>>(xb, gbuck, gcur, eps, w1i, b1, y1, st1);
    gemm2_kernel<<<(N_NODES + 127) / 128, 256, 0, stream>>>(y1, w2i, b2, g1, be1, st1, y2, st2);
    output_kernel<<<N_NODES * DIM / (8 * 256), 256, 0, stream>>>((const u32*)y2, st2,
                                                                 g2, be2, (float*)d_out);
}

// Round 7
// 231.030 us; speedup vs baseline: 3.3759x; 3.3759x over previous
//
#include <hip/hip_runtime.h>
#include <hip/hip_bf16.h>

typedef __hip_bfloat16 bf16;
typedef unsigned short u16;
typedef unsigned int u32;
typedef __attribute__((ext_vector_type(8))) short short8;
typedef __attribute__((ext_vector_type(4))) float floatx4;

#define N_NODES 50000
#define N_EDGES 800000
#define DIM 128
#define NB2 1563           // ceil(50000/32); bucket = dst >> 5
#define NB2A 1792          // padded
#define CAP2 768           // per-bucket capacity (mean 512, sd ~23 -> 11 sigma)
#define T_EDGES 4096       // edges per sort1 tile -> 196 tiles
#define NT1 196            // sort1 blocks in K1
#define XCHUNKS 3125       // x-convert chunks (2048 floats each)
#define WROW 136           // padded W row stride (u16): 272B, 16B-aligned
#define WIMG (128 * WROW)  // 17408 u16 per W image
// stats: sum at stats[l*2048 + c*16], sq at [.. + 8] -> one 64B line per accumulator
// LDS atomics: int = native ds ops (cheap, used in sorts); float = NOT native (r6: 6x regression)

__device__ __forceinline__ u16 f2bfbits(float f) {
    bf16 h = __float2bfloat16(f);
    return *(u16*)&h;
}
__device__ __forceinline__ unsigned pack2(float a, float b) {
    return (unsigned)f2bfbits(a) | ((unsigned)f2bfbits(b) << 16);
}
__device__ __forceinline__ float lo2f(u32 u) { u32 v = u << 16; return __builtin_bit_cast(float, v); }
__device__ __forceinline__ float hi2f(u32 u) { u32 v = u & 0xFFFF0000u; return __builtin_bit_cast(float, v); }
__device__ __forceinline__ float b162f(u16 u) { u32 v = (u32)u << 16; return __builtin_bit_cast(float, v); }

// ---------------- K1: sort1 tiles (bid<196) || x->bf16 || W->bf16 images ----------------
__launch_bounds__(256)
__global__ void k1_kernel(const float* __restrict__ x, const int* __restrict__ ei,
                          u32* __restrict__ xb,
                          const float* __restrict__ W1, const float* __restrict__ W2,
                          u16* __restrict__ w1i, u16* __restrict__ w2i,
                          u32* __restrict__ gbuck, int* __restrict__ gcur) {
    __shared__ int hist[NB2A];
    __shared__ int cur[NB2A];
    __shared__ int gbase[NB2A];
    __shared__ int sdet;
    int t = threadIdx.x, bid = blockIdx.x;

    if (bid < NT1) {
        if (t == 0) sdet = 0;
        for (int i = t; i < NB2A; i += 256) { hist[i] = 0; cur[i] = 0; }
        __syncthreads();
        if (t < 64) { if (ei[2 * t + 1] != 0) atomicOr(&sdet, 1); }
        __syncthreads();
        int is64 = (sdet == 0);
        int e0 = bid * T_EDGES;
        int n = N_EDGES - e0; if (n > T_EDGES) n = T_EDGES;
        u32 ed[T_EDGES / 256];
        #pragma unroll
        for (int j = 0; j < T_EDGES / 256; j++) {
            int idx = j * 256 + t;
            if (idx < n) {
                int e = e0 + idx;
                int js = e, jd = N_EDGES + e;
                if (is64) { js = 2 * e; jd = 2 * (N_EDGES + e); }
                u32 p = (u32)ei[js] | ((u32)ei[jd] << 16);
                ed[j] = p;
                atomicAdd(&hist[p >> 21], 1);      // bucket = dst>>5 = p>>21
            }
        }
        __syncthreads();
        // reserve dense global runs; gcur stride-16: one 64B line per bucket counter
        for (int i = t; i < NB2; i += 256) {
            int c = hist[i];
            gbase[i] = c ? atomicAdd(&gcur[i * 16], c) : 0;
        }
        __syncthreads();
        #pragma unroll
        for (int j = 0; j < T_EDGES / 256; j++) {
            int idx = j * 256 + t;
            if (idx < n) {
                u32 p = ed[j];
                int b = p >> 21;
                int pos = gbase[b] + atomicAdd(&cur[b], 1);
                gbuck[(long)b * CAP2 + pos] = p;
            }
        }
    } else if (bid < NT1 + XCHUNKS) {
        int uu = bid - NT1;
        int i = (uu * 256 + t) * 8;
        floatx4 v0 = *(const floatx4*)&x[i];
        floatx4 v1 = *(const floatx4*)&x[i + 4];
        uint4 r;
        r.x = pack2(v0[0], v0[1]); r.y = pack2(v0[2], v0[3]);
        r.z = pack2(v1[0], v1[1]); r.w = pack2(v1[2], v1[3]);
        *(uint4*)&xb[i / 2] = r;
    } else {
        int which = bid - NT1 - XCHUNKS;           // 0 or 1
        const float* W = which ? W2 : W1;
        u16* wi = which ? w2i : w1i;
        #pragma unroll 4
        for (int j = 0; j < 68; j++) {             // 68*256 = 17408 exactly
            int q = j * 256 + t;
            int r = q / WROW, c = q - r * WROW;
            wi[q] = (c < 128) ? f2bfbits(W[r * 128 + c]) : (u16)0;
        }
    }
}

// ---------------- K2 v3: in-LDS sort + uint2 pair-interleaved gather (one bucket/block) ----------------
// 32 lanes/row, 2 edges per load instruction; each wave interleaves 2 nodes' lists
// -> 8 load-instrs = 16 edges in flight. Self term folded pre-reduce; shfl_xor(32) reduce.
__launch_bounds__(256)
__global__ void sortagg_kernel(const u32* __restrict__ xb, const u32* __restrict__ gbuck,
                               const int* __restrict__ gcur, const float* __restrict__ epsp,
                               u32* __restrict__ hw) {
    __shared__ u32 sbuf[CAP2];       // 3 KB
    __shared__ u16 slist[CAP2];      // 1.5 KB
    __shared__ int cnt[32], offs[32], cur[32];
    int t = threadIdx.x, lane = t & 63, wv = t >> 6;
    int h = lane >> 5, q = lane & 31;
    int b = blockIdx.x;
    int n = gcur[b * 16]; if (n > CAP2) n = CAP2;
    long base = (long)b * CAP2;
    const uint2* xb2 = (const uint2*)xb;

    if (t < 32) { cnt[t] = 0; cur[t] = 0; }
    __syncthreads();
    for (int i = t; i < n; i += 256) {
        u32 p = gbuck[base + i];
        sbuf[i] = p;
        atomicAdd(&cnt[(p >> 16) & 31], 1);        // LDS int atomic: native, cheap
    }
    __syncthreads();
    if (t < 32) {                    // wave-0 shfl prefix over 32 counters
        int v = cnt[t], pv = v;
        #pragma unroll
        for (int d = 1; d < 32; d <<= 1) { int up = __shfl_up(pv, d); if (t >= d) pv += up; }
        offs[t] = pv - v;            // exclusive
    }
    __syncthreads();
    for (int i = t; i < n; i += 256) {
        u32 p = sbuf[i];
        int d = (p >> 16) & 31;
        int pos = offs[d] + atomicAdd(&cur[d], 1);
        slist[pos] = (u16)(p & 0xFFFF);
    }
    __syncthreads();

    float ep1 = 1.0f + epsp[0];
    for (int p = wv; p < 16; p += 4) {             // pair p: nodes 2p, 2p+1
        int nA = 2 * p, nB = 2 * p + 1;
        int nodeS = b * 32 + 2 * p + h;            // this half's self node
        int sOK = nodeS < N_NODES;
        uint2 sS = xb2[(size_t)(sOK ? nodeS : 0) * 32 + q];   // self row, issued early
        int iA = offs[nA], eA = iA + cnt[nA];
        int iB = offs[nB], eB = iB + cnt[nB];
        float a0 = 0.f, a1 = 0.f, a2 = 0.f, a3 = 0.f;
        float c0 = 0.f, c1 = 0.f, c2 = 0.f, c3 = 0.f;

        // joint 8-edge-per-node batches: 8 load instrs = 16 edges in flight
        while (iA + 8 <= eA && iB + 8 <= eB) {
            int mA[4], mB[4]; uint2 uA[4], uB[4];
            #pragma unroll
            for (int j = 0; j < 4; j++) { mA[j] = slist[iA + 2 * j + h]; mB[j] = slist[iB + 2 * j + h]; }
            #pragma unroll
            for (int j = 0; j < 4; j++) { uA[j] = xb2[(size_t)mA[j] * 32 + q]; uB[j] = xb2[(size_t)mB[j] * 32 + q]; }
            #pragma unroll
            for (int j = 0; j < 4; j++) {
                a0 += lo2f(uA[j].x); a1 += hi2f(uA[j].x); a2 += lo2f(uA[j].y); a3 += hi2f(uA[j].y);
                c0 += lo2f(uB[j].x); c1 += hi2f(uB[j].x); c2 += lo2f(uB[j].y); c3 += hi2f(uB[j].y);
            }
            iA += 8; iB += 8;
        }
        while (iA + 8 <= eA) {                     // drain A
            int mA[4]; uint2 uA[4];
            #pragma unroll
            for (int j = 0; j < 4; j++) mA[j] = slist[iA + 2 * j + h];
            #pragma unroll
            for (int j = 0; j < 4; j++) uA[j] = xb2[(size_t)mA[j] * 32 + q];
            #pragma unroll
            for (int j = 0; j < 4; j++) {
                a0 += lo2f(uA[j].x); a1 += hi2f(uA[j].x); a2 += lo2f(uA[j].y); a3 += hi2f(uA[j].y);
            }
            iA += 8;
        }
        while (iB + 8 <= eB) {                     // drain B
            int mB[4]; uint2 uB[4];
            #pragma unroll
            for (int j = 0; j < 4; j++) mB[j] = slist[iB + 2 * j + h];
            #pragma unroll
            for (int j = 0; j < 4; j++) uB[j] = xb2[(size_t)mB[j] * 32 + q];
            #pragma unroll
            for (int j = 0; j < 4; j++) {
                c0 += lo2f(uB[j].x); c1 += hi2f(uB[j].x); c2 += lo2f(uB[j].y); c3 += hi2f(uB[j].y);
            }
            iB += 8;
        }
        // masked joint tail: up to 4 edges per node per iter (4 load instrs in flight)
        while (iA < eA || iB < eB) {
            int ia0 = iA + h, ia1 = iA + 2 + h, ib0 = iB + h, ib1 = iB + 2 + h;
            int va0 = ia0 < eA, va1 = ia1 < eA, vb0 = ib0 < eB, vb1 = ib1 < eB;
            int mA0 = slist[va0 ? ia0 : 0], mA1 = slist[va1 ? ia1 : 0];
            int mB0 = slist[vb0 ? ib0 : 0], mB1 = slist[vb1 ? ib1 : 0];
            uint2 uA0 = xb2[(size_t)mA0 * 32 + q], uA1 = xb2[(size_t)mA1 * 32 + q];
            uint2 uB0 = xb2[(size_t)mB0 * 32 + q], uB1 = xb2[(size_t)mB1 * 32 + q];
            if (va0) { a0 += lo2f(uA0.x); a1 += hi2f(uA0.x); a2 += lo2f(uA0.y); a3 += hi2f(uA0.y); }
            if (va1) { a0 += lo2f(uA1.x); a1 += hi2f(uA1.x); a2 += lo2f(uA1.y); a3 += hi2f(uA1.y); }
            if (vb0) { c0 += lo2f(uB0.x); c1 += hi2f(uB0.x); c2 += lo2f(uB0.y); c3 += hi2f(uB0.y); }
            if (vb1) { c0 += lo2f(uB1.x); c1 += hi2f(uB1.x); c2 += lo2f(uB1.y); c3 += hi2f(uB1.y); }
            iA += 4; iB += 4;
        }
        // fold self term (half h holds node 2p+h's row)
        if (sOK) {
            if (h == 0) {
                a0 += ep1 * lo2f(sS.x); a1 += ep1 * hi2f(sS.x);
                a2 += ep1 * lo2f(sS.y); a3 += ep1 * hi2f(sS.y);
            } else {
                c0 += ep1 * lo2f(sS.x); c1 += ep1 * hi2f(sS.x);
                c2 += ep1 * lo2f(sS.y); c3 += ep1 * hi2f(sS.y);
            }
        }
        // cross-half reduce: both halves end with full sums
        a0 += __shfl_xor(a0, 32); a1 += __shfl_xor(a1, 32);
        a2 += __shfl_xor(a2, 32); a3 += __shfl_xor(a3, 32);
        c0 += __shfl_xor(c0, 32); c1 += __shfl_xor(c1, 32);
        c2 += __shfl_xor(c2, 32); c3 += __shfl_xor(c3, 32);
        // half h stores node 2p+h
        float r0 = h ? c0 : a0, r1 = h ? c1 : a1, r2 = h ? c2 : a2, r3 = h ? c3 : a3;
        if (sOK) {
            uint2 w; w.x = pack2(r0, r1); w.y = pack2(r2, r3);
            *(uint2*)&hw[(size_t)nodeS * 64 + 2 * q] = w;
        }
    }
}

// ---------------- K3: MFMA GEMM, 128 rows/block, 2 tiles/wave, LDS-staged bf16 W image ----------------
template<int TRANSFORM>
__launch_bounds__(256)
__global__ void gemm_mfma(const u16* __restrict__ Ap, const u16* __restrict__ wimg,
                          const float* __restrict__ bias,
                          const float* __restrict__ gamma, const float* __restrict__ beta,
                          const float* __restrict__ gstat,
                          u16* __restrict__ Yp, float* __restrict__ ostat) {
    __shared__ u16 sW[WIMG];                                   // 34816 B padded image
    __shared__ float sScale[128], sShift[128], sBias[128], sSum[128], sSq[128];
    int t = threadIdx.x, lane = t & 63, wv = t >> 6;

    #pragma unroll
    for (int it = 0; it < 9; it++) {
        int q = it * 256 + t;
        if (q < WIMG / 8) *(uint4*)&sW[q * 8] = ((const uint4*)wimg)[q];
    }
    if (t < 128) {
        sSum[t] = 0.f; sSq[t] = 0.f; sBias[t] = bias[t];
        if (TRANSFORM) {
            float m = gstat[t * 16] * (1.0f / N_NODES);
            float v = fmaxf(gstat[t * 16 + 8] * (1.0f / N_NODES) - m * m, 0.0f);
            float rs = rsqrtf(v + 1e-5f);
            float sc = gamma[t] * rs;
            sScale[t] = sc;
            sShift[t] = beta[t] - m * sc;
        }
    }
    __syncthreads();

    int col0 = lane & 15, quad = lane >> 4;
    int row0 = blockIdx.x * 128 + wv * 32;

    short8 afr[2][4];
    #pragma unroll
    for (int tt = 0; tt < 2; tt++) {
        int mrow = row0 + tt * 16 + col0;
        if (mrow > N_NODES - 1) mrow = N_NODES - 1;            // clamp inside A
        #pragma unroll
        for (int ks = 0; ks < 4; ks++)
            afr[tt][ks] = *(const short8*)&Ap[mrow * DIM + ks * 32 + quad * 8];
    }
    if (TRANSFORM) {
        #pragma unroll
        for (int tt = 0; tt < 2; tt++)
            #pragma unroll
            for (int ks = 0; ks < 4; ks++) {
                int kb = ks * 32 + quad * 8;
                short8 a = afr[tt][ks], r;
                #pragma unroll
                for (int j = 0; j < 8; j++) {
                    float f = b162f((u16)a[j]);
                    r[j] = (short)f2bfbits(fmaxf(fmaf(f, sScale[kb + j], sShift[kb + j]), 0.f));
                }
                afr[tt][ks] = r;
            }
    }

    floatx4 acc[2][8];
    #pragma unroll
    for (int tt = 0; tt < 2; tt++)
        #pragma unroll
        for (int nt = 0; nt < 8; nt++) acc[tt][nt] = (floatx4){0.f, 0.f, 0.f, 0.f};
    #pragma unroll
    for (int ks = 0; ks < 4; ks++)
        #pragma unroll
        for (int nt = 0; nt < 8; nt++) {
            short8 bfr = *(const short8*)&sW[(nt * 16 + col0) * WROW + ks * 32 + quad * 8];
            acc[0][nt] = __builtin_amdgcn_mfma_f32_16x16x32_bf16(afr[0][ks], bfr, acc[0][nt], 0, 0, 0);
            acc[1][nt] = __builtin_amdgcn_mfma_f32_16x16x32_bf16(afr[1][ks], bfr, acc[1][nt], 0, 0, 0);
        }

    #pragma unroll
    for (int tt = 0; tt < 2; tt++) {
        int rtile = row0 + tt * 16;
        if (rtile >= N_NODES) break;                           // tiles 16-aligned; N%16==0
        #pragma unroll
        for (int nt = 0; nt < 8; nt++) {
            int col = nt * 16 + col0;
            float bb = sBias[col];
            float o0 = acc[tt][nt][0] + bb, o1 = acc[tt][nt][1] + bb;
            float o2 = acc[tt][nt][2] + bb, o3 = acc[tt][nt][3] + bb;
            int rbase = rtile + quad * 4;
            Yp[(rbase + 0) * DIM + col] = f2bfbits(o0);
            Yp[(rbase + 1) * DIM + col] = f2bfbits(o1);
            Yp[(rbase + 2) * DIM + col] = f2bfbits(o2);
            Yp[(rbase + 3) * DIM + col] = f2bfbits(o3);
            float s = o0 + o1 + o2 + o3;
            float q = o0 * o0 + o1 * o1 + o2 * o2 + o3 * o3;
            s += __shfl_xor(s, 16); s += __shfl_xor(s, 32);
            q += __shfl_xor(q, 16); q += __shfl_xor(q, 32);
            if (quad == 0) { atomicAdd(&sSum[col], s); atomicAdd(&sSq[col], q); }
        }
    }
    __syncthreads();
    if (t < 128) {
        atomicAdd(&ostat[t * 16], sSum[t]);
        atomicAdd(&ostat[t * 16 + 8], sSq[t]);
    }
}

// ---------------- K4: final BN2 + ReLU: y2 bf16 -> out fp32 ----------------
__global__ void output_kernel(const u32* __restrict__ Y,
                              const float* __restrict__ gstat,
                              const float* __restrict__ gamma, const float* __restrict__ beta,
                              float* __restrict__ out) {
    __shared__ float sScale[128], sShift[128];
    int t = threadIdx.x;
    if (t < 128) {
        float m = gstat[t * 16] * (1.0f / N_NODES);
        float v = fmaxf(gstat[t * 16 + 8] * (1.0f / N_NODES) - m * m, 0.0f);
        float rs = rsqrtf(v + 1e-5f);
        float sc = gamma[t] * rs;
        sScale[t] = sc;
        sShift[t] = beta[t] - m * sc;
    }
    __syncthreads();
    int i = (blockIdx.x * 256 + t) * 8;
    int c = i & 127;
    uint4 v = *(const uint4*)&Y[i / 2];
    u32 w[4] = {v.x, v.y, v.z, v.w};
    floatx4 o0, o1;
    #pragma unroll
    for (int j = 0; j < 4; j++) {
        float lo = lo2f(w[j]), hi = hi2f(w[j]);
        float r0 = fmaxf(fmaf(lo, sScale[c + 2 * j],     sShift[c + 2 * j]),     0.f);
        float r1 = fmaxf(fmaf(hi, sScale[c + 2 * j + 1], sShift[c + 2 * j + 1]), 0.f);
        if (j < 2) { o0[2 * j] = r0; o0[2 * j + 1] = r1; }
        else       { o1[2 * (j - 2)] = r0; o1[2 * (j - 2) + 1] = r1; }
    }
    *(floatx4*)&out[i] = o0;
    *(floatx4*)&out[i + 4] = o1;
}

extern "C" void kernel_launch(void* const* d_in, const int* in_sizes, int n_in,
                              void* d_out, int out_size, void* d_ws, size_t ws_size,
                              hipStream_t stream) {
    const float* x   = (const float*)d_in[0];
    const int* eraw  = (const int*)d_in[1];
    const float* eps = (const float*)d_in[3];
    const float* W1  = (const float*)d_in[4];
    const float* b1  = (const float*)d_in[5];
    const float* g1  = (const float*)d_in[6];
    const float* be1 = (const float*)d_in[7];
    const float* W2  = (const float*)d_in[8];
    const float* b2  = (const float*)d_in[9];
    const float* g2  = (const float*)d_in[10];
    const float* be2 = (const float*)d_in[11];

    char* ws = (char*)d_ws;
    size_t off = 0;
    u32* xb = (u32*)(ws + off);          off += (size_t)N_NODES * DIM * 2;   // bf16 x
    u32* h1 = (u32*)(ws + off);          off += (size_t)N_NODES * DIM * 2;   // bf16 h
    u16* y1 = (u16*)(ws + off);          off += (size_t)N_NODES * DIM * 2;   // bf16 y1
    u16* y2 = (u16*)(ws + off);          off += (size_t)N_NODES * DIM * 2;   // bf16 y2
    float* stats = (float*)(ws + off);   off += 4096 * 4;                    // strided stats
    float* st1 = stats;                  // layer-1: sum @ [c*16], sq @ [c*16+8]
    float* st2 = stats + 2048;           // layer-2
    u16* w1i = (u16*)(ws + off);         off += (size_t)WIMG * 2;            // bf16 W1 image
    u16* w2i = (u16*)(ws + off);         off += (size_t)WIMG * 2;            // bf16 W2 image
    u32* gbuck = (u32*)(ws + off);       off += (size_t)NB2 * CAP2 * 4;      // 4.8 MB
    int* gcur = (int*)(ws + off);        off += (size_t)((NB2 * 16 + 255) & ~255) * 4;

    hipMemsetAsync(gcur, 0, (size_t)NB2 * 16 * 4, stream);
    hipMemsetAsync(stats, 0, 4096 * 4, stream);

    k1_kernel<<<NT1 + XCHUNKS + 2, 256, 0, stream>>>(x, eraw, xb, W1, W2, w1i, w2i, gbuck, gcur);
    sortagg_kernel<<<NB2, 256, 0, stream>>>(xb, gbuck, gcur, eps, h1);

    const int gemmGrid = (N_NODES + 127) / 128;  // 391 blocks, 128 rows each
    gemm_mfma<0><<<gemmGrid, 256, 0, stream>>>((const u16*)h1, w1i, b1,
                                               nullptr, nullptr, nullptr, y1, st1);
    gemm_mfma<1><<<gemmGrid, 256, 0, stream>>>(y1, w2i, b2,
                                               g1, be1, st1, y2, st2);
    output_kernel<<<N_NODES * DIM / (8 * 256), 256, 0, stream>>>((const u32*)y2, st2,
                                                                 g2, be2, (float*)d_out);
}